// Round 6
// baseline (407.694 us; speedup 1.0000x reference)
//
#include <hip/hip_runtime.h>
#include <hip/hip_bf16.h>
#include <stdint.h>

// MutualCrossAttention: B=8, C=64, H=W=64 -> T=4096 tokens. Inputs FP32, output FP32.
// dir A: Q=x1, K=V=x2 ; dir B: Q=x2, K=V=x1 ; out = outA + outB, layout [b][c][t].
// Dataflow mirrors the m120-verified composition exactly:
//   S = QK^T with A=Q, B=K  -> P in C/D layout (row=q=quad*4+reg, col=tok=l16)
//   P -> LDS (row-major [q][tok]) -> re-read as A-operand frags
//   O = PV with A=P, B=V    -> out in C/D layout (row=q, col=c)
// ws: 8 MB = xt (bf16 token-major copies of x1,x2). V converted from fp32 in-loop.

#define TT 4096
#define CC 64
#define NB 8
#define PSTR 72  // plds row stride in ushorts (144B = 16B-aligned rows)

typedef float f32x4 __attribute__((ext_vector_type(4)));
typedef float f32x4a __attribute__((ext_vector_type(4), may_alias));
typedef short s16x8 __attribute__((ext_vector_type(8)));  // MFMA operand (register value)
typedef unsigned int u32x2a __attribute__((ext_vector_type(2), may_alias));
typedef unsigned int u32x4a __attribute__((ext_vector_type(4), may_alias));

static __device__ __forceinline__ unsigned fbits(float x) { return __float_as_uint(x); }
// f32 -> bf16 (round-half-up)
static __device__ __forceinline__ ushort bf16of(float v) {
    return (ushort)((fbits(v) + 0x8000u) >> 16);
}
// pack two f32 -> bf16x2 in one u32: low16 = a, high16 = b
static __device__ __forceinline__ unsigned pack2(float a, float b) {
    return __builtin_amdgcn_perm(fbits(b) + 0x8000u, fbits(a) + 0x8000u, 0x07060302u);
}
static __device__ __forceinline__ s16x8 load_frag(const void* p) {
    u32x4a t = *(const u32x4a*)p;
    return __builtin_bit_cast(s16x8, t);
}
// 8 consecutive fp32 -> bf16x8 fragment (ascending, low16 first)
static __device__ __forceinline__ s16x8 cvt_frag(const float* p) {
    f32x4a a = *(const f32x4a*)p;
    f32x4a b = *(const f32x4a*)(p + 4);
    u32x4a u;
    u[0] = pack2(a[0], a[1]);
    u[1] = pack2(a[2], a[3]);
    u[2] = pack2(b[0], b[1]);
    u[3] = pack2(b[2], b[3]);
    return __builtin_bit_cast(s16x8, u);
}

// Read fp32 x[inp][b][c][t]; emit bf16 token-major xt[inp][b][t][c].
__global__ void prep_k(const float* __restrict__ x1, const float* __restrict__ x2,
                       ushort* __restrict__ xt) {
    const int inp = blockIdx.z, b = blockIdx.y, t0 = blockIdx.x * 64;
    const float* src = (inp == 0 ? x1 : x2) + (size_t)b * CC * TT;
    ushort* xd = xt + (size_t)(inp * NB + b) * (size_t)TT * CC;
    const int tid = threadIdx.x;
    const int t = t0 + (tid >> 2);
    const int c0 = (tid & 3) * 16;
    unsigned w[8];
#pragma unroll
    for (int j = 0; j < 8; ++j) {
        float lo = src[(size_t)(c0 + 2 * j) * TT + t];
        float hi = src[(size_t)(c0 + 2 * j + 1) * TT + t];
        w[j] = pack2(lo, hi);
    }
    u32x4a* o = (u32x4a*)(xd + (size_t)t * CC + c0);
    u32x4a v0 = {w[0], w[1], w[2], w[3]};
    u32x4a v1 = {w[4], w[5], w[6], w[7]};
    o[0] = v0;
    o[1] = v1;
}

// Block = (b, 64 q-rows), 4 waves: waves 0-1 dir A (Q=x1), waves 2-3 dir B (Q=x2).
// Wave w and w+2 share a q-range; dir-B pushes scaled acc via LDS, dir-A sums and
// writes final fp32. grid = 64*8 = 512; b = blockIdx.x & 7 pins batch per XCD.
__global__ __launch_bounds__(256, 2)
void attn_fused_k(const float* __restrict__ x1, const float* __restrict__ x2,
                  const ushort* __restrict__ xt, float* __restrict__ out) {
    const int b    = blockIdx.x & 7;
    const int qt   = blockIdx.x >> 3;  // [0,64)
    const int tid  = threadIdx.x;
    const int wave = tid >> 6;
    const int lane = tid & 63;
    const int quad = lane >> 4;
    const int l16  = lane & 15;
    const int pair = wave & 1;
    const int dir  = wave >> 1;
    const int q0   = qt * 64 + pair * 32;

    const size_t plane = (size_t)TT * CC;
    const ushort* Qb = xt + (size_t)((dir == 0 ? 0 : NB) + b) * plane;  // token-major bf16
    const ushort* Kb = xt + (size_t)((dir == 0 ? NB : 0) + b) * plane;  // token-major bf16
    const float*  Vb = (dir == 0 ? x2 : x1) + (size_t)b * plane;        // c-major fp32

    // P per wave: row-major [q(16)][tok(64)], row stride 72 ushorts (144B, 16B-aligned).
    __shared__ __align__(16) ushort plds[4][2][16][PSTR];
    // dirB -> dirA exchange: [pair][32 acc slots][lane].
    __shared__ float xbuf[2][32][64];

    // Q a-frags: A[m=q=l16][k=c=quad*8+j], loaded once.
    s16x8 qf[2][2];
#pragma unroll
    for (int rb = 0; rb < 2; ++rb)
#pragma unroll
        for (int ch = 0; ch < 2; ++ch)
            qf[rb][ch] = load_frag(Qb + (size_t)(q0 + rb * 16 + l16) * CC + ch * 32 + quad * 8);

    f32x4 accO[2][4];  // O acc (C/D layout): row=q=quad*4+r (+rb*16), col=c=l16 (+ct*16)
#pragma unroll
    for (int rb = 0; rb < 2; ++rb)
#pragma unroll
        for (int ct = 0; ct < 4; ++ct) accO[rb][ct] = (f32x4){0.f, 0.f, 0.f, 0.f};
    float lp[2][4];  // softmax denom partials per own q-row (q = rb*16 + quad*4 + r)
#pragma unroll
    for (int rb = 0; rb < 2; ++rb)
#pragma unroll
        for (int r = 0; r < 4; ++r) lp[rb][r] = 0.f;

    const float C1 = 0.18033688011112042f;  // log2(e)/8 (folds 1/sqrt(64))
    const ushort* kp  = Kb + l16 * CC + quad * 8;
    const float*  vpb = Vb + (size_t)l16 * TT + quad * 8;

#pragma unroll 1
    for (int kt = 0; kt < TT / 64; ++kt) {
        const int k0 = kt * 64;
        // K b-frags: B[n=tok=l16][k=c=quad*8+j], contiguous 16B from token-major.
        s16x8 kf[4][2];
#pragma unroll
        for (int nt = 0; nt < 4; ++nt)
#pragma unroll
            for (int ch = 0; ch < 2; ++ch)
                kf[nt][ch] = load_frag(kp + (size_t)(k0 + nt * 16) * CC + ch * 32);

        // S = Q·K^T: D[row=q=quad*4+r][col=tok=l16 (+nt*16)].
#pragma unroll
        for (int rb = 0; rb < 2; ++rb)
#pragma unroll
            for (int nt = 0; nt < 4; ++nt) {
                f32x4 s = (f32x4){0.f, 0.f, 0.f, 0.f};
                s = __builtin_amdgcn_mfma_f32_16x16x32_bf16(qf[rb][0], kf[nt][0], s, 0, 0, 0);
                s = __builtin_amdgcn_mfma_f32_16x16x32_bf16(qf[rb][1], kf[nt][1], s, 0, 0, 0);
#pragma unroll
                for (int r = 0; r < 4; ++r) {
                    float p = __builtin_amdgcn_exp2f(fminf(s[r] * C1, 30.f));
                    lp[rb][r] += p;
                    plds[wave][rb][quad * 4 + r][nt * 16 + l16] = bf16of(p);
                }
            }

        // Drain P writes; block reordering of the reads below.
        __asm__ __volatile__("s_waitcnt lgkmcnt(0)" ::: "memory");

        // O += P·V: A=P[m=q=l16][k=tok=quad*8+j] (b128 from LDS),
        //           B=V[n=c=l16][k=tok=quad*8+j] (cvt from c-major fp32).
#pragma unroll
        for (int ch2 = 0; ch2 < 2; ++ch2) {
            s16x8 pf[2];
#pragma unroll
            for (int rb = 0; rb < 2; ++rb)
                pf[rb] = load_frag(&plds[wave][rb][l16][ch2 * 32 + quad * 8]);
#pragma unroll
            for (int ct = 0; ct < 4; ++ct) {
                s16x8 vf = cvt_frag(vpb + (size_t)(ct * 16) * TT + k0 + ch2 * 32);
#pragma unroll
                for (int rb = 0; rb < 2; ++rb)
                    accO[rb][ct] = __builtin_amdgcn_mfma_f32_16x16x32_bf16(pf[rb], vf, accO[rb][ct], 0, 0, 0);
            }
        }
    }

    // Softmax denominators: each lane's lp[rb][r] covers tokens ≡ l16 (mod 16);
    // butterfly over l16 bits completes the sum for q = q0 + rb*16 + quad*4 + r.
    float inv[2][4];
#pragma unroll
    for (int rb = 0; rb < 2; ++rb)
#pragma unroll
        for (int r = 0; r < 4; ++r) {
            float l = lp[rb][r];
            l += __shfl_xor(l, 1);
            l += __shfl_xor(l, 2);
            l += __shfl_xor(l, 4);
            l += __shfl_xor(l, 8);
            inv[rb][r] = __builtin_amdgcn_rcpf(l);
        }

    if (dir == 1) {
#pragma unroll
        for (int rb = 0; rb < 2; ++rb)
#pragma unroll
            for (int ct = 0; ct < 4; ++ct)
#pragma unroll
                for (int r = 0; r < 4; ++r)
                    xbuf[pair][rb * 16 + ct * 4 + r][lane] = accO[rb][ct][r] * inv[rb][r];
    }
    __syncthreads();
    if (dir == 0) {
        float* ob = out + (size_t)b * plane;
#pragma unroll
        for (int rb = 0; rb < 2; ++rb)
#pragma unroll
            for (int ct = 0; ct < 4; ++ct) {
                f32x4a v;
#pragma unroll
                for (int r = 0; r < 4; ++r)
                    v[r] = accO[rb][ct][r] * inv[rb][r] + xbuf[pair][rb * 16 + ct * 4 + r][lane];
                // out[c = ct*16+l16][t = q0 + rb*16 + quad*4 + r]: 4 consecutive t,
                // 16B-aligned (t offset multiple of 4) -> dwordx4 store
                *(f32x4a*)(ob + (size_t)(ct * 16 + l16) * TT + q0 + rb * 16 + quad * 4) = v;
            }
    }
}

extern "C" void kernel_launch(void* const* d_in, const int* in_sizes, int n_in,
                              void* d_out, int out_size, void* d_ws, size_t ws_size,
                              hipStream_t stream) {
    const float* x1 = (const float*)d_in[0];  // fp32 per reference setup_inputs
    const float* x2 = (const float*)d_in[1];
    ushort* xt = (ushort*)d_ws;  // 2*8*4096*64 bf16 = 8 MB

    hipLaunchKernelGGL(prep_k, dim3(TT / 64, NB, 2), dim3(256), 0, stream, x1, x2, xt);
    hipLaunchKernelGGL(attn_fused_k, dim3(64 * NB), dim3(256), 0, stream,
                       x1, x2, xt, (float*)d_out);
}

// Round 7
// 327.913 us; speedup vs baseline: 1.2433x; 1.2433x over previous
//
#include <hip/hip_runtime.h>
#include <hip/hip_bf16.h>
#include <stdint.h>

// MutualCrossAttention: B=8, C=64, H=W=64 -> T=4096 tokens. Inputs FP32, output FP32.
// dir A: Q=x1, K=V=x2 ; dir B: Q=x2, K=V=x1 ; out = outA + outB, layout [b][c][t].
// Composition (R6-validated): S = QK^T (A=Q,B=K) -> P (C/D layout) -> LDS -> A-frags;
// O = PV (A=P,B=V) -> C/D layout epilogue. R7: software-pipelined K/V register
// prefetch + ping-pong P buffer + bf16 V plane (vt) to cut in-loop cvt VALU.
// ws: [0,8MB) xt bf16 token-major {x1,x2}; [8MB,16MB) vt bf16 c-major {x1,x2}.

#define TT 4096
#define CC 64
#define NB 8

typedef float f32x4 __attribute__((ext_vector_type(4)));
typedef float f32x4a __attribute__((ext_vector_type(4), may_alias));
typedef short s16x8 __attribute__((ext_vector_type(8)));  // MFMA operand (register value)
typedef unsigned int u32x2a __attribute__((ext_vector_type(2), may_alias));
typedef unsigned int u32x4a __attribute__((ext_vector_type(4), may_alias));

static __device__ __forceinline__ unsigned fbits(float x) { return __float_as_uint(x); }
// f32 -> bf16 (round-half-up)
static __device__ __forceinline__ ushort bf16of(float v) {
    return (ushort)((fbits(v) + 0x8000u) >> 16);
}
// pack two f32 -> bf16x2 in one u32: low16 = a, high16 = b
static __device__ __forceinline__ unsigned pack2(float a, float b) {
    return __builtin_amdgcn_perm(fbits(b) + 0x8000u, fbits(a) + 0x8000u, 0x07060302u);
}
static __device__ __forceinline__ s16x8 load_frag(const void* p) {
    u32x4a t = *(const u32x4a*)p;
    return __builtin_bit_cast(s16x8, t);
}

// Read fp32 x[inp][b][c][t] in 64x64 tiles; emit bf16 token-major xt[inp][b][t][c]
// (via LDS transpose, coalesced both sides) and bf16 c-major vt[inp][b][c][t].
__global__ void prep_k(const float* __restrict__ x1, const float* __restrict__ x2,
                       ushort* __restrict__ xt, ushort* __restrict__ vt) {
    const int inp = blockIdx.z, b = blockIdx.y, t0 = blockIdx.x * 64;
    const float* src = (inp == 0 ? x1 : x2) + (size_t)b * CC * TT;
    const size_t plane = (size_t)TT * CC;
    ushort* xd = xt + (size_t)(inp * NB + b) * plane;
    ushort* vd = vt + (size_t)(inp * NB + b) * plane;
    __shared__ ushort lds[64][72];  // [t][c], stride 72 (144B rows, 16B-aligned)
    const int tid = threadIdx.x;
    const int c  = tid >> 2;   // 0..63
    const int tg = tid & 3;    // 16-token group -> thread covers 16 consecutive t
    const float* srow = src + (size_t)c * TT + t0 + tg * 16;
    unsigned hw[8];
#pragma unroll
    for (int i = 0; i < 4; ++i) {
        f32x4a v = *(const f32x4a*)(srow + i * 4);  // coalesced 1KB/16-lane row-chunk
        hw[2 * i]     = pack2(v[0], v[1]);
        hw[2 * i + 1] = pack2(v[2], v[3]);
#pragma unroll
        for (int k = 0; k < 4; ++k) lds[tg * 16 + i * 4 + k][c] = bf16of(v[k]);
    }
    // vt: 16 consecutive bf16 tokens per thread -> two 16B stores, 128B/4-lane segs
    ushort* vrow = vd + (size_t)c * TT + t0 + tg * 16;
    u32x4a w0 = {hw[0], hw[1], hw[2], hw[3]};
    u32x4a w1 = {hw[4], hw[5], hw[6], hw[7]};
    *(u32x4a*)(vrow) = w0;
    *(u32x4a*)(vrow + 8) = w1;
    __syncthreads();
    // xt: row t = 64 bf16 channels = 128B -> 8 threads x 16B, coalesced
#pragma unroll
    for (int pass = 0; pass < 2; ++pass) {
        const int t  = (tid >> 3) + pass * 32;
        const int c8 = (tid & 7) * 8;
        u32x4a w = *(const u32x4a*)&lds[t][c8];
        *(u32x4a*)(xd + (size_t)(t0 + t) * CC + c8) = w;
    }
}

// Block = (b, 64 q-rows), 4 waves: waves 0-1 dir A (Q=x1), waves 2-3 dir B (Q=x2).
// Software-pipelined K-loop: register-double-buffered K/V frags, ping-pong P LDS
// buffer (PV consumes P from iter kt-1 while S(kt) computes). No barriers in loop.
__global__ __launch_bounds__(256, 2)
void attn_fused_k(const ushort* __restrict__ xt, const ushort* __restrict__ vt,
                  float* __restrict__ out) {
    const int b    = blockIdx.x & 7;
    const int qt   = blockIdx.x >> 3;  // [0,64)
    const int tid  = threadIdx.x;
    const int wave = tid >> 6;
    const int lane = tid & 63;
    const int quad = lane >> 4;
    const int l16  = lane & 15;
    const int pair = wave & 1;
    const int dir  = wave >> 1;
    const int q0   = qt * 64 + pair * 32;

    const size_t plane = (size_t)TT * CC;
    const ushort* Qb = xt + (size_t)((dir == 0 ? 0 : NB) + b) * plane;  // token-major
    const ushort* Kb = xt + (size_t)((dir == 0 ? NB : 0) + b) * plane;  // token-major
    const ushort* Vb = vt + (size_t)((dir == 0 ? NB : 0) + b) * plane;  // c-major

    // Ping-pong P: [pp][wave][rb][q16][tok], row stride 72 (16B-aligned, wave-private).
    __shared__ __align__(16) ushort pbuf[2][4][2][16][72];  // 36 KB
    // dirB -> dirA exchange: [pair][32 acc slots][lane].
    __shared__ float xbuf[2][32][64];  // 16 KB

    // Q a-frags: A[m=q=l16][k=c=quad*8+j], loaded once.
    s16x8 qf[2][2];
#pragma unroll
    for (int rb = 0; rb < 2; ++rb)
#pragma unroll
        for (int ch = 0; ch < 2; ++ch)
            qf[rb][ch] = load_frag(Qb + (size_t)(q0 + rb * 16 + l16) * CC + ch * 32 + quad * 8);

    f32x4 accO[2][4];  // O acc (C/D): row=q=quad*4+r (+rb*16), col=c=l16 (+ct*16)
#pragma unroll
    for (int rb = 0; rb < 2; ++rb)
#pragma unroll
        for (int ct = 0; ct < 4; ++ct) accO[rb][ct] = (f32x4){0.f, 0.f, 0.f, 0.f};
    float lp[2][4];
#pragma unroll
    for (int rb = 0; rb < 2; ++rb)
#pragma unroll
        for (int r = 0; r < 4; ++r) lp[rb][r] = 0.f;

    const float C1 = 0.18033688011112042f;  // log2(e)/8 (folds 1/sqrt(64))
    const ushort* kp = Kb + l16 * CC + quad * 8;
    const ushort* vp = Vb + (size_t)l16 * TT + quad * 8;

    // Register double buffers
    s16x8 kf[2][4][2];   // [slot][nt][ch]
    s16x8 vf[2][2][4];   // [slot][ch2][ct]
    s16x8 pf[2][2];      // [ch2][rb]

    // Prologue: K(0), V(0) -> slot 0
#pragma unroll
    for (int nt = 0; nt < 4; ++nt)
#pragma unroll
        for (int ch = 0; ch < 2; ++ch)
            kf[0][nt][ch] = load_frag(kp + (size_t)(nt * 16) * CC + ch * 32);
#pragma unroll
    for (int ch2 = 0; ch2 < 2; ++ch2)
#pragma unroll
        for (int ct = 0; ct < 4; ++ct)
            vf[0][ch2][ct] = load_frag(vp + (size_t)(ct * 16) * TT + ch2 * 32);

#pragma unroll 2
    for (int kt = 0; kt < TT / 64; ++kt) {
        const int cur = kt & 1, nxt = cur ^ 1;
        const int k0n = (kt + 1) * 64;
        // (1) prefetch K(kt+1)
        if (kt < 63) {
#pragma unroll
            for (int nt = 0; nt < 4; ++nt)
#pragma unroll
                for (int ch = 0; ch < 2; ++ch)
                    kf[nxt][nt][ch] = load_frag(kp + (size_t)(k0n + nt * 16) * CC + ch * 32);
        }
        // (2) issue P(kt-1) reads early (latency hidden under QK)
        if (kt > 0) {
#pragma unroll
            for (int ch2 = 0; ch2 < 2; ++ch2)
#pragma unroll
                for (int rb = 0; rb < 2; ++rb)
                    pf[ch2][rb] = load_frag(&pbuf[nxt][wave][rb][l16][ch2 * 32 + quad * 8]);
        }
        // (3) S(kt) = Q·K^T: D[row=q=quad*4+r][col=tok=l16 (+nt*16)]
        f32x4 sv[2][4];
#pragma unroll
        for (int rb = 0; rb < 2; ++rb)
#pragma unroll
            for (int nt = 0; nt < 4; ++nt) {
                f32x4 s = (f32x4){0.f, 0.f, 0.f, 0.f};
                s = __builtin_amdgcn_mfma_f32_16x16x32_bf16(qf[rb][0], kf[cur][nt][0], s, 0, 0, 0);
                sv[rb][nt] = __builtin_amdgcn_mfma_f32_16x16x32_bf16(qf[rb][1], kf[cur][nt][1], s, 0, 0, 0);
            }
        // (4) PV(kt-1): A=P (pf), B=V(kt-1) = vf[nxt] (slot (kt-1)&1 = nxt)
        if (kt > 0) {
#pragma unroll
            for (int ch2 = 0; ch2 < 2; ++ch2)
#pragma unroll
                for (int ct = 0; ct < 4; ++ct)
#pragma unroll
                    for (int rb = 0; rb < 2; ++rb)
                        accO[rb][ct] = __builtin_amdgcn_mfma_f32_16x16x32_bf16(
                            pf[ch2][rb], vf[nxt][ch2][ct], accO[rb][ct], 0, 0, 0);
        }
        // (5) prefetch V(kt+1) into slot nxt (freed by PV above)
        if (kt < 63) {
#pragma unroll
            for (int ch2 = 0; ch2 < 2; ++ch2)
#pragma unroll
                for (int ct = 0; ct < 4; ++ct)
                    vf[nxt][ch2][ct] = load_frag(vp + (size_t)(ct * 16) * TT + k0n + ch2 * 32);
        }
        // (6) softmax-numerator P(kt) -> pbuf[cur]
#pragma unroll
        for (int rb = 0; rb < 2; ++rb)
#pragma unroll
            for (int nt = 0; nt < 4; ++nt)
#pragma unroll
                for (int r = 0; r < 4; ++r) {
                    float p = __builtin_amdgcn_exp2f(fminf(sv[rb][nt][r] * C1, 30.f));
                    lp[rb][r] += p;
                    pbuf[cur][wave][rb][quad * 4 + r][nt * 16 + l16] = bf16of(p);
                }
    }
    // Tail: PV(63) from pbuf[1], vf[1]
#pragma unroll
    for (int ch2 = 0; ch2 < 2; ++ch2)
#pragma unroll
        for (int rb = 0; rb < 2; ++rb)
            pf[ch2][rb] = load_frag(&pbuf[1][wave][rb][l16][ch2 * 32 + quad * 8]);
#pragma unroll
    for (int ch2 = 0; ch2 < 2; ++ch2)
#pragma unroll
        for (int ct = 0; ct < 4; ++ct)
#pragma unroll
            for (int rb = 0; rb < 2; ++rb)
                accO[rb][ct] = __builtin_amdgcn_mfma_f32_16x16x32_bf16(
                    pf[ch2][rb], vf[1][ch2][ct], accO[rb][ct], 0, 0, 0);

    // Softmax denominators: lane's lp covers tokens ≡ l16 (mod 16); butterfly l16 bits.
    float inv[2][4];
#pragma unroll
    for (int rb = 0; rb < 2; ++rb)
#pragma unroll
        for (int r = 0; r < 4; ++r) {
            float l = lp[rb][r];
            l += __shfl_xor(l, 1);
            l += __shfl_xor(l, 2);
            l += __shfl_xor(l, 4);
            l += __shfl_xor(l, 8);
            inv[rb][r] = __builtin_amdgcn_rcpf(l);
        }

    if (dir == 1) {
#pragma unroll
        for (int rb = 0; rb < 2; ++rb)
#pragma unroll
            for (int ct = 0; ct < 4; ++ct)
#pragma unroll
                for (int r = 0; r < 4; ++r)
                    xbuf[pair][rb * 16 + ct * 4 + r][lane] = accO[rb][ct][r] * inv[rb][r];
    }
    __syncthreads();
    if (dir == 0) {
        float* ob = out + (size_t)b * plane;
#pragma unroll
        for (int rb = 0; rb < 2; ++rb)
#pragma unroll
            for (int ct = 0; ct < 4; ++ct) {
                f32x4a v;
#pragma unroll
                for (int r = 0; r < 4; ++r)
                    v[r] = accO[rb][ct][r] * inv[rb][r] + xbuf[pair][rb * 16 + ct * 4 + r][lane];
                *(f32x4a*)(ob + (size_t)(ct * 16 + l16) * TT + q0 + rb * 16 + quad * 4) = v;
            }
    }
}

extern "C" void kernel_launch(void* const* d_in, const int* in_sizes, int n_in,
                              void* d_out, int out_size, void* d_ws, size_t ws_size,
                              hipStream_t stream) {
    const float* x1 = (const float*)d_in[0];  // fp32 per reference setup_inputs
    const float* x2 = (const float*)d_in[1];
    ushort* xt = (ushort*)d_ws;                              // 8 MB
    ushort* vt = (ushort*)d_ws + (size_t)2 * NB * TT * CC;   // 8 MB (region validated in R3)

    hipLaunchKernelGGL(prep_k, dim3(TT / 64, NB, 2), dim3(256), 0, stream, x1, x2, xt, vt);
    hipLaunchKernelGGL(attn_fused_k, dim3(64 * NB), dim3(256), 0, stream,
                       xt, vt, (float*)d_out);
}

// Round 8
// 301.961 us; speedup vs baseline: 1.3502x; 1.0859x over previous
//
#include <hip/hip_runtime.h>
#include <hip/hip_bf16.h>
#include <stdint.h>

// MutualCrossAttention: B=8, C=64, H=W=64 -> T=4096 tokens. Inputs FP32, output FP32.
// dir A: Q=x1, K=V=x2 ; dir B: Q=x2, K=V=x1 ; out = outA + outB, layout [b][c][t].
// R8: split-K. Block = 512 threads = 8 waves = (pair: q-half, dir, ks: token-half).
// No online-max => split-K partials combine by pure addition (lp and accO), merged
// in LDS at the epilogue. 4096 waves total -> 4 waves/SIMD (2x R7's latency hiding).
// ws: [0,8MB) xt bf16 token-major {x1,x2}; [8MB,16MB) vt bf16 c-major {x1,x2}.

#define TT 4096
#define CC 64
#define NB 8

typedef float f32x4 __attribute__((ext_vector_type(4)));
typedef float f32x4a __attribute__((ext_vector_type(4), may_alias));
typedef short s16x8 __attribute__((ext_vector_type(8)));  // MFMA operand (register value)
typedef unsigned int u32x4a __attribute__((ext_vector_type(4), may_alias));

static __device__ __forceinline__ unsigned fbits(float x) { return __float_as_uint(x); }
static __device__ __forceinline__ ushort bf16of(float v) {
    return (ushort)((fbits(v) + 0x8000u) >> 16);
}
static __device__ __forceinline__ unsigned pack2(float a, float b) {
    return __builtin_amdgcn_perm(fbits(b) + 0x8000u, fbits(a) + 0x8000u, 0x07060302u);
}
static __device__ __forceinline__ s16x8 load_frag(const void* p) {
    u32x4a t = *(const u32x4a*)p;
    return __builtin_bit_cast(s16x8, t);
}

// Read fp32 x[inp][b][c][t] in 64x64 tiles; emit bf16 token-major xt[inp][b][t][c]
// (via LDS transpose) and bf16 c-major vt[inp][b][c][t].
__global__ void prep_k(const float* __restrict__ x1, const float* __restrict__ x2,
                       ushort* __restrict__ xt, ushort* __restrict__ vt) {
    const int inp = blockIdx.z, b = blockIdx.y, t0 = blockIdx.x * 64;
    const float* src = (inp == 0 ? x1 : x2) + (size_t)b * CC * TT;
    const size_t plane = (size_t)TT * CC;
    ushort* xd = xt + (size_t)(inp * NB + b) * plane;
    ushort* vd = vt + (size_t)(inp * NB + b) * plane;
    __shared__ ushort lds[64][72];
    const int tid = threadIdx.x;
    const int c  = tid >> 2;
    const int tg = tid & 3;
    const float* srow = src + (size_t)c * TT + t0 + tg * 16;
    unsigned hw[8];
#pragma unroll
    for (int i = 0; i < 4; ++i) {
        f32x4a v = *(const f32x4a*)(srow + i * 4);
        hw[2 * i]     = pack2(v[0], v[1]);
        hw[2 * i + 1] = pack2(v[2], v[3]);
#pragma unroll
        for (int k = 0; k < 4; ++k) lds[tg * 16 + i * 4 + k][c] = bf16of(v[k]);
    }
    ushort* vrow = vd + (size_t)c * TT + t0 + tg * 16;
    u32x4a w0 = {hw[0], hw[1], hw[2], hw[3]};
    u32x4a w1 = {hw[4], hw[5], hw[6], hw[7]};
    *(u32x4a*)(vrow) = w0;
    *(u32x4a*)(vrow + 8) = w1;
    __syncthreads();
#pragma unroll
    for (int pass = 0; pass < 2; ++pass) {
        const int t  = (tid >> 3) + pass * 32;
        const int c8 = (tid & 7) * 8;
        u32x4a w = *(const u32x4a*)&lds[t][c8];
        *(u32x4a*)(xd + (size_t)(t0 + t) * CC + c8) = w;
    }
}

// grid = 512 blocks (qt 0..63 x b 0..7), 512 threads = 8 waves.
// wave: pair = w&1 (q 32-row half), dir = (w>>1)&1, ks = w>>2 (token half).
__global__ __launch_bounds__(512, 4)
void attn_fused_k(const ushort* __restrict__ xt, const ushort* __restrict__ vt,
                  float* __restrict__ out) {
    const int b    = blockIdx.x & 7;
    const int qt   = blockIdx.x >> 3;
    const int tid  = threadIdx.x;
    const int wave = tid >> 6;      // 0..7
    const int lane = tid & 63;
    const int quad = lane >> 4;
    const int l16  = lane & 15;
    const int pair = wave & 1;
    const int dir  = (wave >> 1) & 1;
    const int ks   = wave >> 2;
    const int g    = (ks << 1) | dir;  // epilogue phase group
    const int q0   = qt * 64 + pair * 32;

    const size_t plane = (size_t)TT * CC;
    const ushort* Qb = xt + (size_t)((dir == 0 ? 0 : NB) + b) * plane;
    const ushort* Kb = xt + (size_t)((dir == 0 ? NB : 0) + b) * plane;
    const ushort* Vb = vt + (size_t)((dir == 0 ? NB : 0) + b) * plane;

    // P per wave: [q16][tok64], stride 72 ushorts (144B, 16B-aligned rows).
    __shared__ __align__(16) ushort pbuf[8][2][16][72];  // 36.9 KB
    __shared__ float xbuf[2][32][64];                    // 16.4 KB
    __shared__ float lpx[8][2][4][4];                    // 1 KB

    // Q a-frags: A[m=q=l16][k=c=quad*8+j], loaded once.
    s16x8 qf[2][2];
#pragma unroll
    for (int rb = 0; rb < 2; ++rb)
#pragma unroll
        for (int ch = 0; ch < 2; ++ch)
            qf[rb][ch] = load_frag(Qb + (size_t)(q0 + rb * 16 + l16) * CC + ch * 32 + quad * 8);

    f32x4 accO[2][4];  // O partial (C/D): row=q=quad*4+r (+rb*16), col=c=l16 (+ct*16)
#pragma unroll
    for (int rb = 0; rb < 2; ++rb)
#pragma unroll
        for (int ct = 0; ct < 4; ++ct) accO[rb][ct] = (f32x4){0.f, 0.f, 0.f, 0.f};
    float lp[2][4];
#pragma unroll
    for (int rb = 0; rb < 2; ++rb)
#pragma unroll
        for (int r = 0; r < 4; ++r) lp[rb][r] = 0.f;

    const float C1 = 0.18033688011112042f;  // log2(e)/8 (folds 1/sqrt(64))
    const ushort* kp = Kb + l16 * CC + quad * 8;
    const ushort* vp = Vb + (size_t)l16 * TT + quad * 8;

    const int kt0 = ks * 32;
#pragma unroll 1
    for (int kt = kt0; kt < kt0 + 32; ++kt) {
        const int k0 = kt * 64;
        // S = Q·K^T per 16-token group; P -> LDS immediately (short live ranges).
#pragma unroll
        for (int nt = 0; nt < 4; ++nt) {
            s16x8 kf0 = load_frag(kp + (size_t)(k0 + nt * 16) * CC);
            s16x8 kf1 = load_frag(kp + (size_t)(k0 + nt * 16) * CC + 32);
#pragma unroll
            for (int rb = 0; rb < 2; ++rb) {
                f32x4 s = (f32x4){0.f, 0.f, 0.f, 0.f};
                s = __builtin_amdgcn_mfma_f32_16x16x32_bf16(qf[rb][0], kf0, s, 0, 0, 0);
                s = __builtin_amdgcn_mfma_f32_16x16x32_bf16(qf[rb][1], kf1, s, 0, 0, 0);
#pragma unroll
                for (int r = 0; r < 4; ++r) {
                    float p = __builtin_amdgcn_exp2f(fminf(s[r] * C1, 30.f));
                    lp[rb][r] += p;
                    pbuf[wave][rb][quad * 4 + r][nt * 16 + l16] = bf16of(p);
                }
            }
        }
        // O += P·V: A=P (b128 from LDS), B=V[n=c=l16][k=tok=quad*8+j] (bf16 global).
#pragma unroll
        for (int ch2 = 0; ch2 < 2; ++ch2) {
            s16x8 pf[2];
#pragma unroll
            for (int rb = 0; rb < 2; ++rb)
                pf[rb] = load_frag(&pbuf[wave][rb][l16][ch2 * 32 + quad * 8]);
            s16x8 vf[4];
#pragma unroll
            for (int ct = 0; ct < 4; ++ct)
                vf[ct] = load_frag(vp + (size_t)(ct * 16) * TT + k0 + ch2 * 32);
#pragma unroll
            for (int ct = 0; ct < 4; ++ct)
#pragma unroll
                for (int rb = 0; rb < 2; ++rb)
                    accO[rb][ct] = __builtin_amdgcn_mfma_f32_16x16x32_bf16(
                        pf[rb], vf[ct], accO[rb][ct], 0, 0, 0);
        }
    }

    // lp butterfly over l16 bits -> this wave's token-half denominator per q.
#pragma unroll
    for (int rb = 0; rb < 2; ++rb)
#pragma unroll
        for (int r = 0; r < 4; ++r) {
            float l = lp[rb][r];
            l += __shfl_xor(l, 1);
            l += __shfl_xor(l, 2);
            l += __shfl_xor(l, 4);
            l += __shfl_xor(l, 8);
            lp[rb][r] = l;
            if (l16 == 0) lpx[wave][rb][quad][r] = l;
        }
    __syncthreads();
    // Total denominator: add the ks-partner wave's half (same pair,dir).
    float inv[2][4];
#pragma unroll
    for (int rb = 0; rb < 2; ++rb)
#pragma unroll
        for (int r = 0; r < 4; ++r)
            inv[rb][r] = __builtin_amdgcn_rcpf(lp[rb][r] + lpx[wave ^ 4][rb][quad][r]);

    // Staged accumulation into xbuf[pair]: g==3 writes, then g==2, g==1 add, g==0 adds+stores.
    if (g == 3) {
#pragma unroll
        for (int rb = 0; rb < 2; ++rb)
#pragma unroll
            for (int ct = 0; ct < 4; ++ct)
#pragma unroll
                for (int r = 0; r < 4; ++r)
                    xbuf[pair][rb * 16 + ct * 4 + r][lane] = accO[rb][ct][r] * inv[rb][r];
    }
    __syncthreads();
    if (g == 2) {
#pragma unroll
        for (int rb = 0; rb < 2; ++rb)
#pragma unroll
            for (int ct = 0; ct < 4; ++ct)
#pragma unroll
                for (int r = 0; r < 4; ++r)
                    xbuf[pair][rb * 16 + ct * 4 + r][lane] += accO[rb][ct][r] * inv[rb][r];
    }
    __syncthreads();
    if (g == 1) {
#pragma unroll
        for (int rb = 0; rb < 2; ++rb)
#pragma unroll
            for (int ct = 0; ct < 4; ++ct)
#pragma unroll
                for (int r = 0; r < 4; ++r)
                    xbuf[pair][rb * 16 + ct * 4 + r][lane] += accO[rb][ct][r] * inv[rb][r];
    }
    __syncthreads();
    if (g == 0) {
        float* ob = out + (size_t)b * plane;
#pragma unroll
        for (int rb = 0; rb < 2; ++rb)
#pragma unroll
            for (int ct = 0; ct < 4; ++ct) {
                f32x4a v;
#pragma unroll
                for (int r = 0; r < 4; ++r)
                    v[r] = accO[rb][ct][r] * inv[rb][r] + xbuf[pair][rb * 16 + ct * 4 + r][lane];
                *(f32x4a*)(ob + (size_t)(ct * 16 + l16) * TT + q0 + rb * 16 + quad * 4) = v;
            }
    }
}

extern "C" void kernel_launch(void* const* d_in, const int* in_sizes, int n_in,
                              void* d_out, int out_size, void* d_ws, size_t ws_size,
                              hipStream_t stream) {
    const float* x1 = (const float*)d_in[0];
    const float* x2 = (const float*)d_in[1];
    ushort* xt = (ushort*)d_ws;                              // 8 MB
    ushort* vt = (ushort*)d_ws + (size_t)2 * NB * TT * CC;   // 8 MB

    hipLaunchKernelGGL(prep_k, dim3(TT / 64, NB, 2), dim3(256), 0, stream, x1, x2, xt, vt);
    hipLaunchKernelGGL(attn_fused_k, dim3(64 * NB), dim3(512), 0, stream,
                       xt, vt, (float*)d_out);
}